// Round 12
// baseline (154.628 us; speedup 1.0000x reference)
//
#include <hip/hip_runtime.h>
#include <stdint.h>

// Fused attention head: out = softmax(mask((Tgt@Wq)(Src@Wk)^T * H^-0.5)) @ (Src@Wv)
// B=4096, T=128, C=128, H=64. 512 threads (8 waves). R12: each block processes
// NBATCH=4 batches with cross-batch software pipelining — next batch's Q rows /
// src half A / mask are issued at B5 (regs dead there) and land under the
// ~2000cy softmax+PV tail, so steady-state batches start with data resident.
// Per-batch structure = R11 (proven): lean front, Q direct from global,
// wave-private LDS bounces for Q and P.

typedef uint32_t u32x2 __attribute__((ext_vector_type(2)));
typedef uint32_t u32x4 __attribute__((ext_vector_type(4)));
typedef float    f32x4 __attribute__((ext_vector_type(4)));
typedef __bf16   bf16x8 __attribute__((ext_vector_type(8)));

#define NBATCH 4

static __device__ __forceinline__ uint32_t pack2(float a, float b) {  // RNE (prep kernel)
  uint32_t ua = __builtin_bit_cast(uint32_t, a);
  uint32_t ub = __builtin_bit_cast(uint32_t, b);
  ua += 0x7FFFu + ((ua >> 16) & 1u);
  ub += 0x7FFFu + ((ub >> 16) & 1u);
  return (ua >> 16) | (ub & 0xFFFF0000u);
}
// compiler-generated f32->bf16 RNE pair (HW-proven R9/R10/R11)
static __device__ __forceinline__ uint32_t cvt2(float a, float b) {
  uint16_t lo = __builtin_bit_cast(uint16_t, (__bf16)a);
  uint16_t hi = __builtin_bit_cast(uint16_t, (__bf16)b);
  return (uint32_t)lo | ((uint32_t)hi << 16);
}
static __device__ __forceinline__ f32x4 mfma16(u32x4 a, u32x4 b, f32x4 c) {
  return __builtin_amdgcn_mfma_f32_16x16x32_bf16(
      __builtin_bit_cast(bf16x8, a), __builtin_bit_cast(bf16x8, b), c, 0, 0, 0);
}

// ---- prep: pack Wq/Wk/Wv into MFMA frag layout in ws; detect mask dtype ----
// frag f=(m*4+ct)*4+ks, lane l: 8 bf16 of W[c][h], h=ct*16+(l&15), c=ks*32+(l>>4)*8+0..7.
// Serves BOTH as B-frag of W (V proj) and A-frag of W^T (K/Q proj).
__global__ void prep_w(const float* __restrict__ Wq, const float* __restrict__ Wk,
                       const float* __restrict__ Wv, const void* __restrict__ mask,
                       uint32_t* __restrict__ ws) {
  const int blk = blockIdx.x;
  const int l = threadIdx.x;  // 0..63
  if (blk < 48) {
    const int m  = blk >> 4;
    const int ct = (blk >> 2) & 3;
    const int ks = blk & 3;
    const float* W = (m == 0) ? Wq : ((m == 1) ? Wk : Wv);
    const int h  = ct * 16 + (l & 15);
    const int c0 = ks * 32 + (l >> 4) * 8;
    u32x4 v;
#pragma unroll
    for (int p = 0; p < 4; ++p)
      v[p] = pack2(W[(c0 + 2 * p) * 64 + h], W[(c0 + 2 * p + 1) * 64 + h]);
    ((u32x4*)ws)[blk * 64 + l] = v;
  } else {
    // mask dtype detect: 0=int32(0/1), 1=bytes, 2=float
    const uint32_t* mw = (const uint32_t*)mask;
    int fl = 0;
    for (int i = l * 16; i < l * 16 + 16; ++i) {
      uint32_t x = mw[i];
      if (x == 0x3F800000u) fl = 2;
      else if (x > 1u && fl != 2) fl = 1;
    }
#pragma unroll
    for (int off = 32; off > 0; off >>= 1) {
      int o = __shfl_down(fl, off);
      fl = (o > fl) ? o : fl;
    }
    if (l == 0) ws[12288] = (uint32_t)fl;
  }
}

// LDS (48.5 KB):
//  EMB [64][128] bf16 swz (16K)  src staging; tail: wave-private Q slice then P rows tl<8
//  Kb  [128][64] bf16 swz (16K)  K[s][h]; tail (after B5): P rows tl>=8
//  Vb  [64][128] bf16 swz (16K)  V^T[h][s]
//  BIAS[128] f32
__global__ __launch_bounds__(512, 2) void attn_fused(
    const float* __restrict__ src, const float* __restrict__ tgt,
    const void* __restrict__ mask, const uint32_t* __restrict__ ws,
    float* __restrict__ out, int Btot) {
  __shared__ __align__(16) uint8_t lds[49664];
  uint8_t* const EMB = lds;
  uint8_t* const Kb  = lds + 16384;
  uint8_t* const Vb  = lds + 32768;
  float*  const BIAS = (float*)(lds + 49152);

  const int tid = (int)threadIdx.x;
  const int l   = tid & 63;
  const int w   = tid >> 6;      // wave 0..7
  const int l15 = l & 15;
  const int g4  = l >> 4;        // 0..3
  const int ct  = w & 3;         // wave's h-tile for K/V projections
  const int sg  = (w >> 2) * 2;  // wave's first local row-tile for K/V (0 or 2)
  const int tq  = 16 * w + l15;  // this lane's output row t

  const u32x4* wsv = (const u32x4*)ws;
  const int mflag = (int)ws[12288];

  int b = blockIdx.x * NBATCH;

  // ---- prefetch state (reused across iterations) ----
  f32x4 qv[8];   // this batch's Q A-frag rows (tgt[tq][.])
  f32x4 pf[4];   // this batch's src half (staging)
  float biasv;

  auto load_q = [&](int bb) {
    const float* pq = tgt + (size_t)bb * 16384 + tq * 128 + g4 * 8;
#pragma unroll
    for (int ks = 0; ks < 4; ++ks) {
      qv[2 * ks]     = *(const f32x4*)(pq + ks * 32);
      qv[2 * ks + 1] = *(const f32x4*)(pq + ks * 32 + 4);
    }
  };
  auto stage_load = [&](const float* gbase) {
#pragma unroll
    for (int p = 0; p < 4; ++p)
      pf[p] = *(const f32x4*)(gbase + tid * 4 + p * 2048);
  };
  auto load_bias = [&](int bb) -> float {
    if (tid >= 128) return 0.0f;
    bool valid;
    if (mflag == 1)      valid = ((const uint8_t*)mask)[bb * 128 + tid] != 0;
    else if (mflag == 0) valid = ((const int*)mask)[bb * 128 + tid] != 0;
    else                 valid = ((const float*)mask)[bb * 128 + tid] != 0.0f;
    return valid ? 0.0f : -1e30f;
  };
  auto stage_write = [&]() {
#pragma unroll
    for (int p = 0; p < 4; ++p) {
      const int c   = tid + p * 512;
      const int row = c >> 5;     // 0..63
      const int cc  = c & 31;     // f32x4 chunk within row
      u32x2 d = { cvt2(pf[p][0], pf[p][1]), cvt2(pf[p][2], pf[p][3]) };
      *(u32x2*)(EMB + (row << 8) + ((((cc >> 1) ^ (row & 7))) << 4) + ((cc & 1) << 3)) = d;
    }
  };

  u32x4 wk[4], wv[4];  // reloaded from L2 each iteration (dead during tail)
  auto projKV = [&](int half) {
#pragma unroll
    for (int i = 0; i < 2; ++i) {
      const int st  = sg + i;            // local 16-row tile 0..3
      const int row = st * 16 + l15;     // EMB row
      f32x4 cK = {0, 0, 0, 0}, cV = {0, 0, 0, 0};
#pragma unroll
      for (int ks = 0; ks < 4; ++ks) {
        u32x4 e = *(const u32x4*)(EMB + (row << 8) + ((((ks * 4 + g4) ^ (row & 7))) << 4));
        cK = mfma16(wk[ks], e, cK);   // C[h][s]
        cV = mfma16(e, wv[ks], cV);   // C[s][h]
      }
      const int s  = half * 64 + st * 16 + l15;       // K: n=s per-lane col
      const int h0 = ct * 16 + g4 * 4;                //    m=h rows (packed pair-write)
      u32x2 dk = { cvt2(cK[0], cK[1]), cvt2(cK[2], cK[3]) };
      *(u32x2*)(Kb + (s << 7) + ((((h0 >> 3) ^ (s & 7))) << 4) + ((h0 & 7) << 1)) = dk;
      const int s0 = half * 64 + st * 16 + g4 * 4;    // V^T: m=s packed, n=h col
      const int h  = ct * 16 + l15;
      u32x2 dv = { cvt2(cV[0], cV[1]), cvt2(cV[2], cV[3]) };
      *(u32x2*)(Vb + (h << 8) + ((((s0 >> 3) ^ (h & 7))) << 4) + ((s0 & 7) << 1)) = dv;
    }
  };

  // ---- cold start: issue batch b's loads ----
  load_q(b);
  stage_load(src + (size_t)b * 16384);
  biasv = load_bias(b);

  for (int bi = 0; bi < NBATCH; ++bi) {
    if (b >= Btot) break;  // uniform per block
    const float* const srcb = src + (size_t)b * 16384;

    // W frags for this iteration (L2-resident, reloaded to keep tail regs low)
#pragma unroll
    for (int ks = 0; ks < 4; ++ks) {
      wk[ks] = wsv[((4 + ct) * 4 + ks) * 64 + l];   // A-frag of Wk^T
      wv[ks] = wsv[((8 + ct) * 4 + ks) * 64 + l];   // B-frag of Wv
    }

    // ---- projQ (consumer-aligned): all 64 h for own t-tile, from qv regs ----
    // qp[ctq*2+p] = bf16x2 of Q^T[h = ctq*16 + g4*4 + 2p + {0,1}][t]
    uint32_t qp[8];
    {
      f32x4 c0 = {0,0,0,0}, c1 = {0,0,0,0}, c2 = {0,0,0,0}, c3 = {0,0,0,0};
#pragma unroll
      for (int ks = 0; ks < 4; ++ks) {
        u32x4 e = { cvt2(qv[2*ks][0], qv[2*ks][1]), cvt2(qv[2*ks][2], qv[2*ks][3]),
                    cvt2(qv[2*ks+1][0], qv[2*ks+1][1]), cvt2(qv[2*ks+1][2], qv[2*ks+1][3]) };
        c0 = mfma16(wsv[(0  + ks) * 64 + l], e, c0);
        c1 = mfma16(wsv[(4  + ks) * 64 + l], e, c1);
        c2 = mfma16(wsv[(8  + ks) * 64 + l], e, c2);
        c3 = mfma16(wsv[(12 + ks) * 64 + l], e, c3);
      }
      qp[0] = cvt2(c0[0], c0[1]); qp[1] = cvt2(c0[2], c0[3]);
      qp[2] = cvt2(c1[0], c1[1]); qp[3] = cvt2(c1[2], c1[3]);
      qp[4] = cvt2(c2[0], c2[1]); qp[5] = cvt2(c2[2], c2[3]);
      qp[6] = cvt2(c3[0], c3[1]); qp[7] = cvt2(c3[2], c3[3]);
    }

    __syncthreads();               // B_head: prev iter's P-slices (EMB/Kb) and
                                   // Vb reads done -> buffers reusable
    stage_write();                 // src half A -> EMB
    if (tid < 128) BIAS[tid] = biasv;
    __syncthreads();               // B1: EMB(A) ready
    stage_load(srcb + 8192);       // half B loads in flight over projKV(0)
    projKV(0);
    __syncthreads();               // B2: EMB(A) reads done
    stage_write();                 // src half B -> EMB
    __syncthreads();               // B3: EMB(B) ready
    projKV(1);
    __syncthreads();               // B4: Kb/Vb/BIAS ready; EMB dead

    // ---- Q bounce: wave-private [16 t][64 h] slice in EMB (2KB/wave) ----
    uint8_t* const Qw = EMB + (w << 11) + (l15 << 7);
#pragma unroll
    for (int ctq = 0; ctq < 4; ++ctq) {
      u32x2 dq = { qp[2 * ctq], qp[2 * ctq + 1] };
      const int cw = ctq * 2 + (g4 >> 1);
      *(u32x2*)(Qw + (((cw ^ (l15 & 7))) << 4) + ((g4 & 1) << 3)) = dq;
    }
    u32x4 qB[2];
#pragma unroll
    for (int ks = 0; ks < 2; ++ks)
      qB[ks] = *(const u32x4*)(Qw + ((((ks * 4 + g4) ^ (l15 & 7))) << 4));

    // ---- S^T = K @ Q^T : per lane col t = tq, rows s = mt*16+g4*4+r ----
    f32x4 sacc[8];
#pragma unroll
    for (int mt = 0; mt < 8; ++mt) sacc[mt] = {0, 0, 0, 0};
    __builtin_amdgcn_s_setprio(1);
#pragma unroll
    for (int mt = 0; mt < 8; ++mt) {
      const int srow = mt * 16 + l15;
      u32x4 k0 = *(const u32x4*)(Kb + (srow << 7) + (((g4 ^ (srow & 7))) << 4));
      u32x4 k1 = *(const u32x4*)(Kb + (srow << 7) + ((((4 + g4) ^ (srow & 7))) << 4));
      sacc[mt] = mfma16(k0, qB[0], sacc[mt]);
      sacc[mt] = mfma16(k1, qB[1], sacc[mt]);
    }
    __builtin_amdgcn_s_setprio(0);

    __syncthreads();               // B5: all QK reads of Kb done -> Kb reusable

    // ---- prefetch NEXT batch (qv/pf/bias regs are dead here); lands under
    //      the softmax+P-bounce+PV+store tail (~2000cy) ----
    if (bi + 1 < NBATCH && b + 1 < Btot) {
      load_q(b + 1);
      stage_load(src + (size_t)(b + 1) * 16384);
      biasv = load_bias(b + 1);
    }

    // ---- softmax over s (32 s-values/lane; reduce across 4-lane group) ----
    float m = -3.0e38f;
#pragma unroll
    for (int mt = 0; mt < 8; ++mt) {
      f32x4 b4 = *(const f32x4*)(BIAS + mt * 16 + g4 * 4);
#pragma unroll
      for (int r = 0; r < 4; ++r) {
        float v = sacc[mt][r] * 0.125f + b4[r];  // scale = H^-0.5 ; pad bias -1e30
        sacc[mt][r] = v;
        m = fmaxf(m, v);
      }
    }
    m = fmaxf(m, __shfl_xor(m, 16));
    m = fmaxf(m, __shfl_xor(m, 32));
    float sum = 0.0f;
#pragma unroll
    for (int mt = 0; mt < 8; ++mt) {
#pragma unroll
      for (int r = 0; r < 4; ++r) {
        const int s = mt * 16 + g4 * 4 + r;
        float p = __expf(sacc[mt][r] - m);
        p = (s <= tq) ? p : 0.0f;               // causal, multiplicative
        sacc[mt][r] = p;
        sum += p;
      }
    }
    sum += __shfl_xor(sum, 16);
    sum += __shfl_xor(sum, 32);
    const float inv = 1.0f / sum;  // >0: col 0 always valid & causal-visible

    // ---- P bounce: wave-private [16 t][128 s] slice in EMB(tl<8)+Kb(tl>=8) ----
    uint8_t* const Pr = (l15 < 8) ? (EMB + (w << 11) + (l15 << 8))
                                  : (Kb + (w << 11) + ((l15 - 8) << 8));
#pragma unroll
    for (int mt = 0; mt < 8; ++mt) {
      u32x2 d = { cvt2(sacc[mt][0], sacc[mt][1]), cvt2(sacc[mt][2], sacc[mt][3]) };
      const int c = mt * 2 + (g4 >> 1);
      *(u32x2*)(Pr + (((c ^ l15)) << 4) + ((g4 & 1) << 3)) = d;
    }

    // ---- OUT^T = V^T @ P^T : A = V^T from Vb rows, B = P from own slice ----
    f32x4 oacc[4];
#pragma unroll
    for (int vt = 0; vt < 4; ++vt) oacc[vt] = {0, 0, 0, 0};
    __builtin_amdgcn_s_setprio(1);
#pragma unroll
    for (int ks = 0; ks < 4; ++ks) {
      u32x4 pb = *(const u32x4*)(Pr + ((((ks * 4 + g4) ^ l15)) << 4));
#pragma unroll
      for (int vt = 0; vt < 4; ++vt) {
        const int vrow = vt * 16 + l15;
        u32x4 vf = *(const u32x4*)(Vb + (vrow << 8) + ((((ks * 4 + g4) ^ (vrow & 7))) << 4));
        oacc[vt] = mfma16(vf, pb, oacc[vt]);
      }
    }
    __builtin_amdgcn_s_setprio(0);

    // epilogue: out[t][h], t = tq, h = vt*16 + g4*4 + r ; fold 1/sum
    float* const ob = out + (size_t)b * 8192 + (size_t)tq * 64;
#pragma unroll
    for (int vt = 0; vt < 4; ++vt) {
      f32x4 o = { oacc[vt][0] * inv, oacc[vt][1] * inv,
                  oacc[vt][2] * inv, oacc[vt][3] * inv };
      *(f32x4*)(ob + vt * 16 + g4 * 4) = o;
    }

    ++b;
  }
}

extern "C" void kernel_launch(void* const* d_in, const int* in_sizes, int n_in,
                              void* d_out, int out_size, void* d_ws, size_t ws_size,
                              hipStream_t stream) {
  const float* src = (const float*)d_in[0];
  const float* tgt = (const float*)d_in[1];
  const void*  msk = d_in[2];
  const float* Wq  = (const float*)d_in[3];
  const float* Wk  = (const float*)d_in[4];
  const float* Wv  = (const float*)d_in[5];
  uint32_t* ws = (uint32_t*)d_ws;  // 48KB W frags + mask-dtype flag
  float* out = (float*)d_out;
  const int B = in_sizes[0] / (128 * 128);
  const int grid = (B + NBATCH - 1) / NBATCH;

  hipLaunchKernelGGL(prep_w, dim3(49), dim3(64), 0, stream, Wq, Wk, Wv, msk, ws);
  hipLaunchKernelGGL(attn_fused, dim3(grid), dim3(512), 0, stream,
                     src, tgt, msk, ws, out, B);
}

// Round 13
// 140.864 us; speedup vs baseline: 1.0977x; 1.0977x over previous
//
#include <hip/hip_runtime.h>
#include <stdint.h>

// Fused attention head: out = softmax(mask((Tgt@Wq)(Src@Wk)^T * H^-0.5)) @ (Src@Wv)
// B=4096, T=128, C=128, H=64. One block/batch, 512 threads (8 waves).
// R13 = R5 (measured champion, 144.8us) + three proven micro-opts:
//  1. pack2 -> cvt2 (compiler bf16 fptrunc; proven R9-R12; R5 was VALU-heaviest)
//  2. s_setprio(1) around QK/PV MFMA (proven R11/R12; barrier-free tail regime)
//  3. drop the redundant post-P-write barrier (R1 precedent: wave-private P
//     bounce needs no block sync; R5 had it as "safety" only)

typedef uint32_t u32x2 __attribute__((ext_vector_type(2)));
typedef uint32_t u32x4 __attribute__((ext_vector_type(4)));
typedef float    f32x4 __attribute__((ext_vector_type(4)));
typedef __bf16   bf16x8 __attribute__((ext_vector_type(8)));

static __device__ __forceinline__ uint32_t pack2(float a, float b) {  // RNE (prep kernel)
  uint32_t ua = __builtin_bit_cast(uint32_t, a);
  uint32_t ub = __builtin_bit_cast(uint32_t, b);
  ua += 0x7FFFu + ((ua >> 16) & 1u);
  ub += 0x7FFFu + ((ub >> 16) & 1u);
  return (ua >> 16) | (ub & 0xFFFF0000u);
}
// compiler-generated f32->bf16 RNE pair (HW-proven R9-R12)
static __device__ __forceinline__ uint32_t cvt2(float a, float b) {
  uint16_t lo = __builtin_bit_cast(uint16_t, (__bf16)a);
  uint16_t hi = __builtin_bit_cast(uint16_t, (__bf16)b);
  return (uint32_t)lo | ((uint32_t)hi << 16);
}
static __device__ __forceinline__ f32x4 mfma16(u32x4 a, u32x4 b, f32x4 c) {
  return __builtin_amdgcn_mfma_f32_16x16x32_bf16(
      __builtin_bit_cast(bf16x8, a), __builtin_bit_cast(bf16x8, b), c, 0, 0, 0);
}

// ---- prep: pack Wq/Wk/Wv into MFMA frag layout in ws; detect mask dtype ----
// frag f=(m*4+ct)*4+ks, lane l: 8 bf16 of W[c][h], h=ct*16+(l&15), c=ks*32+(l>>4)*8+0..7.
// Serves BOTH as B-frag of W (V proj) and A-frag of W^T (K/Q proj).
__global__ void prep_w(const float* __restrict__ Wq, const float* __restrict__ Wk,
                       const float* __restrict__ Wv, const void* __restrict__ mask,
                       uint32_t* __restrict__ ws) {
  const int blk = blockIdx.x;
  const int l = threadIdx.x;  // 0..63
  if (blk < 48) {
    const int m  = blk >> 4;
    const int ct = (blk >> 2) & 3;
    const int ks = blk & 3;
    const float* W = (m == 0) ? Wq : ((m == 1) ? Wk : Wv);
    const int h  = ct * 16 + (l & 15);
    const int c0 = ks * 32 + (l >> 4) * 8;
    u32x4 v;
#pragma unroll
    for (int p = 0; p < 4; ++p)
      v[p] = pack2(W[(c0 + 2 * p) * 64 + h], W[(c0 + 2 * p + 1) * 64 + h]);
    ((u32x4*)ws)[blk * 64 + l] = v;
  } else {
    // mask dtype detect: 0=int32(0/1), 1=bytes, 2=float
    const uint32_t* mw = (const uint32_t*)mask;
    int fl = 0;
    for (int i = l * 16; i < l * 16 + 16; ++i) {
      uint32_t x = mw[i];
      if (x == 0x3F800000u) fl = 2;
      else if (x > 1u && fl != 2) fl = 1;
    }
#pragma unroll
    for (int off = 32; off > 0; off >>= 1) {
      int o = __shfl_down(fl, off);
      fl = (o > fl) ? o : fl;
    }
    if (l == 0) ws[12288] = (uint32_t)fl;
  }
}

// LDS (64.5 KB -> 2 blocks/CU):
//  EMB [64][128] bf16 swz (16K)  staging; later: wave-private P rows t%16 = 0..7
//  Qb  [128][64] bf16 swz (16K)  Q^T store; later: wave-private P rows 8..15
//  Kb  [128][64] bf16 swz (16K)
//  Vb  [64][128] bf16 swz (16K)  (v^T: row=h, col=s)
//  BIAS[128] f32
// Swizzle: 16B chunk c of row r stored at chunk (c ^ (r&7)); P uses (c ^ (t&15)).
__global__ __launch_bounds__(512, 4) void attn_fused(
    const float* __restrict__ src, const float* __restrict__ tgt,
    const void* __restrict__ mask, const uint32_t* __restrict__ ws,
    float* __restrict__ out) {
  __shared__ __align__(16) uint8_t lds[66048];
  uint8_t* const EMB = lds;
  uint8_t* const Qb  = lds + 16384;
  uint8_t* const Kb  = lds + 32768;
  uint8_t* const Vb  = lds + 49152;
  float*  const BIAS = (float*)(lds + 65536);

  const int b   = blockIdx.x;
  const int tid = (int)threadIdx.x;
  const int l   = tid & 63;
  const int w   = tid >> 6;      // wave 0..7
  const int l15 = l & 15;
  const int g4  = l >> 4;        // 0..3
  const int ct  = w & 3;         // this wave's h-tile for projections
  const int sg  = (w >> 2) * 2;  // first local s/t-tile (0 or 2)

  const u32x4* wsv = (const u32x4*)ws;
  const int mflag = (int)ws[12288];
  const float* const srcb = src + (size_t)b * 16384;
  const float* const tgtb = tgt + (size_t)b * 16384;

  u32x4 wk[4], wv[4], wq[4];
#pragma unroll
  for (int ks = 0; ks < 4; ++ks) {
    wk[ks] = wsv[((4 + ct) * 4 + ks) * 64 + l];   // A-frag of Wk^T
    wv[ks] = wsv[((8 + ct) * 4 + ks) * 64 + l];   // B-frag of Wv
  }

  // staging: thread covers 4 fully-coalesced f32x4 chunks (tid + p*512)
  f32x4 pf[4];
  auto stage_load = [&](const float* gbase) {
#pragma unroll
    for (int p = 0; p < 4; ++p)
      pf[p] = *(const f32x4*)(gbase + tid * 4 + p * 2048);
  };
  auto stage_write = [&]() {
#pragma unroll
    for (int p = 0; p < 4; ++p) {
      const int c   = tid + p * 512;
      const int row = c >> 5;     // 0..63
      const int cc  = c & 31;     // f32x4 chunk within row
      u32x2 d = { cvt2(pf[p][0], pf[p][1]), cvt2(pf[p][2], pf[p][3]) };
      *(u32x2*)(EMB + (row << 8) + ((((cc >> 1) ^ (row & 7))) << 4) + ((cc & 1) << 3)) = d;
    }
  };

  // K^T = Wk^T @ Src^T and V = Src @ Wv over one staged 64-row half.
  auto projKV = [&](int half) {
#pragma unroll
    for (int i = 0; i < 2; ++i) {
      const int st  = sg + i;            // local 16-row tile 0..3
      const int row = st * 16 + l15;     // EMB row
      f32x4 cK = {0, 0, 0, 0}, cV = {0, 0, 0, 0};
#pragma unroll
      for (int ks = 0; ks < 4; ++ks) {
        u32x4 e = *(const u32x4*)(EMB + (row << 8) + ((((ks * 4 + g4) ^ (row & 7))) << 4));
        cK = mfma16(wk[ks], e, cK);   // C[h][s]
        cV = mfma16(e, wv[ks], cV);   // C[s][h]
      }
      const int s  = half * 64 + st * 16 + l15;       // K^T: n=s per-lane col
      const int h0 = ct * 16 + g4 * 4;                //      m=h rows (packed)
      u32x2 dk = { cvt2(cK[0], cK[1]), cvt2(cK[2], cK[3]) };
      *(u32x2*)(Kb + (s << 7) + ((((h0 >> 3) ^ (s & 7))) << 4) + ((h0 & 7) << 1)) = dk;
      const int s0 = half * 64 + st * 16 + g4 * 4;    // V: m=s rows (packed)
      const int h  = ct * 16 + l15;                   //    n=h per-lane col
      u32x2 dv = { cvt2(cV[0], cV[1]), cvt2(cV[2], cV[3]) };
      *(u32x2*)(Vb + (h << 8) + ((((s0 >> 3) ^ (h & 7))) << 4) + ((s0 & 7) << 1)) = dv;
    }
  };
  auto projQ = [&](int half) {
#pragma unroll
    for (int i = 0; i < 2; ++i) {
      const int st  = sg + i;
      const int row = st * 16 + l15;
      f32x4 cQ = {0, 0, 0, 0};
#pragma unroll
      for (int ks = 0; ks < 4; ++ks) {
        u32x4 e = *(const u32x4*)(EMB + (row << 8) + ((((ks * 4 + g4) ^ (row & 7))) << 4));
        cQ = mfma16(wq[ks], e, cQ);
      }
      const int t  = half * 64 + st * 16 + l15;
      const int h0 = ct * 16 + g4 * 4;
      u32x2 dq = { cvt2(cQ[0], cQ[1]), cvt2(cQ[2], cQ[3]) };
      *(u32x2*)(Qb + (t << 7) + ((((h0 >> 3) ^ (t & 7))) << 4) + ((h0 & 7) << 1)) = dq;
    }
  };

  // ---- pipeline: loads issued one phase early; full __syncthreads barriers ----
  stage_load(srcb);
  float biasv = 0.0f;
  if (tid < 128) {
    bool valid;
    if (mflag == 1)      valid = ((const uint8_t*)mask)[b * 128 + tid] != 0;
    else if (mflag == 0) valid = ((const int*)mask)[b * 128 + tid] != 0;
    else                 valid = ((const float*)mask)[b * 128 + tid] != 0.0f;
    biasv = valid ? 0.0f : -1e30f;
  }
  stage_write();
  if (tid < 128) BIAS[tid] = biasv;
  __syncthreads();
  stage_load(srcb + 8192);
  projKV(0);
  __syncthreads();
  stage_write();
  __syncthreads();
  stage_load(tgtb);
  projKV(1);
#pragma unroll
  for (int ks = 0; ks < 4; ++ks)
    wq[ks] = wsv[(ct * 4 + ks) * 64 + l];  // A-frag of Wq^T
  __syncthreads();
  stage_write();
  __syncthreads();
  stage_load(tgtb + 8192);
  projQ(0);
  __syncthreads();
  stage_write();
  __syncthreads();
  projQ(1);
  __syncthreads();
  // ------------- no more barriers: waves free-run through QK/softmax/PV -------------

  // S^T = K @ Q^T : wave w owns t-tile w. Per lane: col t = 16w + l15,
  // rows s = mt*16 + g4*4 + r  (C layout: col = lane&15, row = (lane>>4)*4 + reg).
  const int tq = 16 * w + l15;
  u32x4 qf0 = *(const u32x4*)(Qb + (tq << 7) + (((g4 ^ (tq & 7))) << 4));
  u32x4 qf1 = *(const u32x4*)(Qb + (tq << 7) + ((((4 + g4) ^ (tq & 7))) << 4));

  f32x4 sacc[8];
#pragma unroll
  for (int mt = 0; mt < 8; ++mt) sacc[mt] = {0, 0, 0, 0};
  __builtin_amdgcn_s_setprio(1);
#pragma unroll
  for (int mt = 0; mt < 8; ++mt) {
    const int srow = mt * 16 + l15;
    u32x4 k0 = *(const u32x4*)(Kb + (srow << 7) + (((g4 ^ (srow & 7))) << 4));
    u32x4 k1 = *(const u32x4*)(Kb + (srow << 7) + ((((4 + g4) ^ (srow & 7))) << 4));
    sacc[mt] = mfma16(k0, qf0, sacc[mt]);
    sacc[mt] = mfma16(k1, qf1, sacc[mt]);
  }
  __builtin_amdgcn_s_setprio(0);

  // softmax over s (per lane: 32 s-values of row t; reduce across 4-lane group)
  float m = -3.0e38f;
#pragma unroll
  for (int mt = 0; mt < 8; ++mt) {
    f32x4 b4 = *(const f32x4*)(BIAS + mt * 16 + g4 * 4);
#pragma unroll
    for (int r = 0; r < 4; ++r) {
      float v = sacc[mt][r] * 0.125f + b4[r];  // scale = H^-0.5 ; pad bias -1e30
      sacc[mt][r] = v;
      m = fmaxf(m, v);
    }
  }
  m = fmaxf(m, __shfl_xor(m, 16));
  m = fmaxf(m, __shfl_xor(m, 32));
  float sum = 0.0f;
#pragma unroll
  for (int mt = 0; mt < 8; ++mt) {
#pragma unroll
    for (int r = 0; r < 4; ++r) {
      const int s = mt * 16 + g4 * 4 + r;
      float p = __expf(sacc[mt][r] - m);
      p = (s <= tq) ? p : 0.0f;               // causal, multiplicative
      sacc[mt][r] = p;
      sum += p;
    }
  }
  sum += __shfl_xor(sum, 16);
  sum += __shfl_xor(sum, 32);
  const float inv = 1.0f / sum;  // >0: col 0 always valid & causal-visible

  // P bounce through wave-private LDS (EMB rows 8w..8w+7 and own Qb rows dead).
  // Lane holds P[t=16w+l15][s=mt*16+g4*4+0..3] -> P row = l15,
  // chunk c = mt*2+(g4>>1) (^l15 swizzle), 8B half = g4&1.
  // No barrier: slice is wave-private on both sides (R1-proven).
  uint8_t* const Pr = (l15 < 8) ? (EMB + w * 2048 + l15 * 256)
                                : (Qb + w * 2048 + (l15 - 8) * 256);
#pragma unroll
  for (int mt = 0; mt < 8; ++mt) {
    u32x2 d = { cvt2(sacc[mt][0], sacc[mt][1]), cvt2(sacc[mt][2], sacc[mt][3]) };
    const int c = mt * 2 + (g4 >> 1);
    *(u32x2*)(Pr + (((c ^ l15)) << 4) + ((g4 & 1) << 3)) = d;
  }

  // OUT^T = V^T @ P^T : A = V^T from Vb rows, B = P rows (lane row = l15)
  f32x4 oacc[4];
#pragma unroll
  for (int vt = 0; vt < 4; ++vt) oacc[vt] = {0, 0, 0, 0};
  __builtin_amdgcn_s_setprio(1);
#pragma unroll
  for (int ks = 0; ks < 4; ++ks) {
    u32x4 pb = *(const u32x4*)(Pr + ((((ks * 4 + g4) ^ l15)) << 4));
#pragma unroll
    for (int vt = 0; vt < 4; ++vt) {
      const int vrow = vt * 16 + l15;
      u32x4 vf = *(const u32x4*)(Vb + (vrow << 8) + ((((ks * 4 + g4) ^ (vrow & 7))) << 4));
      oacc[vt] = mfma16(vf, pb, oacc[vt]);
    }
  }
  __builtin_amdgcn_s_setprio(0);

  // epilogue: out[t][h], t = 16w + l15, h = vt*16 + g4*4 + r ; fold 1/sum
  float* const ob = out + (size_t)b * 8192 + (size_t)tq * 64;
#pragma unroll
  for (int vt = 0; vt < 4; ++vt) {
    f32x4 o = { oacc[vt][0] * inv, oacc[vt][1] * inv,
                oacc[vt][2] * inv, oacc[vt][3] * inv };
    *(f32x4*)(ob + vt * 16 + g4 * 4) = o;
  }
}

extern "C" void kernel_launch(void* const* d_in, const int* in_sizes, int n_in,
                              void* d_out, int out_size, void* d_ws, size_t ws_size,
                              hipStream_t stream) {
  const float* src = (const float*)d_in[0];
  const float* tgt = (const float*)d_in[1];
  const void*  msk = d_in[2];
  const float* Wq  = (const float*)d_in[3];
  const float* Wk  = (const float*)d_in[4];
  const float* Wv  = (const float*)d_in[5];
  uint32_t* ws = (uint32_t*)d_ws;  // 48KB W frags + mask-dtype flag
  float* out = (float*)d_out;
  const int B = in_sizes[0] / (128 * 128);

  hipLaunchKernelGGL(prep_w, dim3(49), dim3(64), 0, stream, Wq, Wk, Wv, msk, ws);
  hipLaunchKernelGGL(attn_fused, dim3(B), dim3(512), 0, stream,
                     src, tgt, msk, ws, out);
}